// Round 4
// baseline (706.886 us; speedup 1.0000x reference)
//
#include <hip/hip_runtime.h>
#include <math.h>

typedef __attribute__((ext_vector_type(8))) __bf16 bf16x8;
typedef __attribute__((ext_vector_type(4))) float f32x4;

#define PLANE 4096
#define IMG   1048576

__device__ inline ushort f2bf(float f) {
  uint u = __float_as_uint(f);
  u = (u + 0x7fffu + ((u >> 16) & 1u)) >> 16;
  return (ushort)u;
}

union frag_cv { uint4 u; bf16x8 v; };

// ---------------- weight prep: fp32 [co][ci][3][3] -> bf16 [p][cic][co][kk] ----------------
__global__ void k_prep(const float* __restrict__ w1, const float* __restrict__ wd,
                       const float* __restrict__ woff, const float* __restrict__ wmod,
                       const float* __restrict__ wds,
                       ushort* __restrict__ wb1, ushort* __restrict__ wbd,
                       ushort* __restrict__ wbom, ushort* __restrict__ wbds) {
  int stride = gridDim.x * blockDim.x;
  int t0 = blockIdx.x * blockDim.x + threadIdx.x;
  for (int s = t0; s < 9 * 8 * 256 * 32; s += stride) {
    int kk = s & 31, co = (s >> 5) & 255, cic = (s >> 13) & 7, p = s >> 16;
    int ci = cic * 32 + kk;
    wb1[s] = f2bf(w1[(co * 256 + ci) * 9 + p]);
    wbd[s] = f2bf(wd[(co * 256 + ci) * 9 + p]);
  }
  for (int s = t0; s < 9 * 8 * 32 * 32; s += stride) {
    int kk = s & 31, co = (s >> 5) & 31, cic = (s >> 10) & 7, p = s >> 13;
    int ci = cic * 32 + kk;
    float v = 0.f;
    if (co < 18) v = woff[(co * 256 + ci) * 9 + p];
    else if (co < 27) v = wmod[((co - 18) * 256 + ci) * 9 + p];
    wbom[s] = f2bf(v);
  }
  for (int s = t0; s < 8 * 256 * 32; s += stride) {
    int kk = s & 31, co = (s >> 5) & 255, cic = s >> 13;
    wbds[s] = f2bf(wds[co * 256 + cic * 32 + kk]);
  }
}

// ---------------- x NCHW fp32 -> xn NHWC bf16 ----------------
__global__ __launch_bounds__(256) void k_x2nhwc(const float* __restrict__ x,
                                                ushort* __restrict__ xn) {
  __shared__ __align__(16) float sT[64 * 68];
  const int h = blockIdx.x, b = blockIdx.y, t = threadIdx.x;
  for (int chunk = 0; chunk < 4; ++chunk) {
    const int c0 = chunk * 64;
    {
      int w4 = (t & 15) * 4, cl = t >> 4;
      #pragma unroll
      for (int i = 0; i < 4; ++i) {
        int c = cl * 4 + i;
        float4 v = *(const float4*)&x[((b * 256 + c0 + c) * 64 + h) * 64 + w4];
        *(float4*)&sT[c * 68 + w4] = v;
      }
    }
    __syncthreads();
    {
      int w = t & 63, cg = t >> 6;
      #pragma unroll
      for (int i = 0; i < 2; ++i) {
        int cg2 = cg * 2 + i;
        uint ou[4];
        #pragma unroll
        for (int k2 = 0; k2 < 4; ++k2) {
          float lo = sT[(cg2 * 8 + k2 * 2) * 68 + w];
          float hi = sT[(cg2 * 8 + k2 * 2 + 1) * 68 + w];
          ou[k2] = (uint)f2bf(lo) | ((uint)f2bf(hi) << 16);
        }
        *(uint4*)&xn[(((b * 64 + h) * 64 + w) * 256) + c0 + cg2 * 8] = *(uint4*)ou;
      }
    }
    __syncthreads();
  }
}

// ---------------- big conv (3x3 pad1 / 1x1), 256 co, dbuf-B pipeline, bf16 out + stats ----------------
// grid (64,8); 256 thr; wave wv owns co [wv*64, wv*64+64), all 64 px.
template<int NTAP>
__global__ __launch_bounds__(256) void k_convbig(const ushort* __restrict__ an,
                                                 const ushort* __restrict__ wB,
                                                 ushort* __restrict__ ob,
                                                 float* __restrict__ part) {
  __shared__ __align__(16) ushort sA[64 * 264];
  __shared__ __align__(16) ushort sB[2][256 * 40];
  const int h = blockIdx.x, b = blockIdx.y, t = threadIdx.x;
  const int lane = t & 63, wv = t >> 6;
  const int spx = t & 63, seg = t >> 6;
  f32x4 acc[4][4];
  #pragma unroll
  for (int m = 0; m < 4; ++m)
    #pragma unroll
    for (int n = 0; n < 4; ++n) acc[m][n] = (f32x4){0.f, 0.f, 0.f, 0.f};

  uint4 aR[8], bR[4];
  // ---- helpers as macros via lambdas
  auto loadA = [&](int p) {
    int ky = (NTAP == 9) ? p / 3 : 1, kx = (NTAP == 9) ? p % 3 : 1;
    int y = h + ky - 1, sx = spx + kx - 1;
    bool ok = ((unsigned)y < 64u) && ((unsigned)sx < 64u);
    const ushort* src = an + (((b * 64 + y) * 64 + sx) * 256) + seg * 64;
    #pragma unroll
    for (int j = 0; j < 8; ++j) {
      uint4 v = {0u, 0u, 0u, 0u};
      if (ok) v = *(const uint4*)(src + j * 8);
      aR[j] = v;
    }
  };
  auto writeA = [&]() {
    #pragma unroll
    for (int j = 0; j < 8; ++j)
      *(uint4*)&sA[spx * 264 + seg * 64 + j * 8] = aR[j];
  };
  auto loadB = [&](int s) {
    const ushort* srcB = wB + (s * 256 + t) * 32;
    #pragma unroll
    for (int j = 0; j < 4; ++j) bR[j] = *(const uint4*)(srcB + j * 8);
  };
  auto writeB = [&](int buf) {
    #pragma unroll
    for (int j = 0; j < 4; ++j)
      *(uint4*)&sB[buf][t * 40 + j * 8] = bR[j];
  };

  loadA(0); writeA();
  loadB(0); writeB(0);
  __syncthreads();
  int buf = 0;
  for (int p = 0; p < NTAP; ++p) {
    #pragma unroll
    for (int cic = 0; cic < 8; ++cic) {
      const int s = p * 8 + cic;
      const bool last = (s == NTAP * 8 - 1);
      const bool tapEnd = (cic == 7) && (p + 1 < NTAP);
      if (!last) loadB(s + 1);
      if (tapEnd) loadA(p + 1);
      const int krow = lane >> 4;
      bf16x8 af[4], bfr[4];
      #pragma unroll
      for (int m = 0; m < 4; ++m) {
        frag_cv cv;
        cv.u = *(const uint4*)&sA[(m * 16 + (lane & 15)) * 264 + cic * 32 + krow * 8];
        af[m] = cv.v;
      }
      #pragma unroll
      for (int n = 0; n < 4; ++n) {
        frag_cv cv;
        cv.u = *(const uint4*)&sB[buf][(wv * 64 + n * 16 + (lane & 15)) * 40 + krow * 8];
        bfr[n] = cv.v;
      }
      #pragma unroll
      for (int m = 0; m < 4; ++m)
        #pragma unroll
        for (int n = 0; n < 4; ++n)
          acc[m][n] = __builtin_amdgcn_mfma_f32_16x16x32_bf16(af[m], bfr[n], acc[m][n], 0, 0, 0);
      if (!last) writeB(buf ^ 1);
      __syncthreads();
      buf ^= 1;
      if (tapEnd) { writeA(); __syncthreads(); }
    }
  }
  // ---- epilogue: bf16 store + per-block BN partials
  const int row0 = (b * 64 + h) * 64;
  #pragma unroll
  for (int m = 0; m < 4; ++m) {
    int pxo = m * 16 + (lane >> 4) * 4;
    #pragma unroll
    for (int n = 0; n < 4; ++n) {
      int co = wv * 64 + n * 16 + (lane & 15);
      #pragma unroll
      for (int r = 0; r < 4; ++r)
        ob[(row0 + pxo + r) * 256 + co] = f2bf(acc[m][n][r]);
    }
  }
  const int blk = b * 64 + h;
  #pragma unroll
  for (int n = 0; n < 4; ++n) {
    float s1 = 0.f, s2 = 0.f;
    #pragma unroll
    for (int m = 0; m < 4; ++m)
      #pragma unroll
      for (int r = 0; r < 4; ++r) {
        float v = acc[m][n][r];
        s1 += v; s2 += v * v;
      }
    s1 += __shfl_xor(s1, 16); s1 += __shfl_xor(s1, 32);
    s2 += __shfl_xor(s2, 16); s2 += __shfl_xor(s2, 32);
    if (lane < 16) {
      int co = wv * 64 + n * 16 + lane;
      part[blk * 512 + co] = s1;
      part[blk * 512 + 256 + co] = s2;
    }
  }
}

// ---------------- offset/mask conv: 3x3, 32 co, M=128 (2 rows), dbuf-B ----------------
// grid (32,8); wave wv owns m-tiles {wv*2, wv*2+1} (32 px), co 0..31.
__global__ __launch_bounds__(256) void k_convom(const ushort* __restrict__ an,
                                                const ushort* __restrict__ wB,
                                                const float* __restrict__ boff,
                                                const float* __restrict__ bmod,
                                                float* __restrict__ om) {
  __shared__ __align__(16) ushort sA[128 * 264];
  __shared__ __align__(16) ushort sB[2][32 * 40];
  const int h0 = blockIdx.x * 2, b = blockIdx.y, t = threadIdx.x;
  const int lane = t & 63, wv = t >> 6;
  const int spx = t & 63, seg = t >> 6;
  f32x4 acc[2][2];
  #pragma unroll
  for (int m = 0; m < 2; ++m)
    #pragma unroll
    for (int n = 0; n < 2; ++n) acc[m][n] = (f32x4){0.f, 0.f, 0.f, 0.f};

  uint2 bR;
  auto stageA = [&](int p) {
    int ky = p / 3, kx = p % 3;
    #pragma unroll
    for (int rr = 0; rr < 2; ++rr) {
      int y = h0 + rr + ky - 1, sx = spx + kx - 1;
      bool ok = ((unsigned)y < 64u) && ((unsigned)sx < 64u);
      const ushort* src = an + (((b * 64 + y) * 64 + sx) * 256) + seg * 64;
      #pragma unroll
      for (int j = 0; j < 8; ++j) {
        uint4 v = {0u, 0u, 0u, 0u};
        if (ok) v = *(const uint4*)(src + j * 8);
        *(uint4*)&sA[(rr * 64 + spx) * 264 + seg * 64 + j * 8] = v;
      }
    }
  };
  auto loadB = [&](int s) { bR = *(const uint2*)(wB + s * 1024 + t * 4); };
  auto writeB = [&](int buf) {
    int co = t >> 3, c4 = (t & 7) * 4;
    *(uint2*)&sB[buf][co * 40 + c4] = bR;
  };

  stageA(0);
  loadB(0); writeB(0);
  __syncthreads();
  int buf = 0;
  for (int p = 0; p < 9; ++p) {
    #pragma unroll
    for (int cic = 0; cic < 8; ++cic) {
      const int s = p * 8 + cic;
      const bool last = (s == 71);
      const bool tapEnd = (cic == 7) && (p < 8);
      if (!last) loadB(s + 1);
      const int krow = lane >> 4;
      bf16x8 af[2], bfr[2];
      #pragma unroll
      for (int m = 0; m < 2; ++m) {
        frag_cv cv;
        cv.u = *(const uint4*)&sA[((wv * 2 + m) * 16 + (lane & 15)) * 264 + cic * 32 + krow * 8];
        af[m] = cv.v;
      }
      #pragma unroll
      for (int n = 0; n < 2; ++n) {
        frag_cv cv;
        cv.u = *(const uint4*)&sB[buf][(n * 16 + (lane & 15)) * 40 + krow * 8];
        bfr[n] = cv.v;
      }
      #pragma unroll
      for (int m = 0; m < 2; ++m)
        #pragma unroll
        for (int n = 0; n < 2; ++n)
          acc[m][n] = __builtin_amdgcn_mfma_f32_16x16x32_bf16(af[m], bfr[n], acc[m][n], 0, 0, 0);
      if (!last) writeB(buf ^ 1);
      __syncthreads();
      buf ^= 1;
      if (tapEnd) { stageA(p + 1); __syncthreads(); }
    }
  }
  #pragma unroll
  for (int m = 0; m < 2; ++m) {
    int pxf = (wv * 2 + m) * 16 + (lane >> 4) * 4;
    #pragma unroll
    for (int n = 0; n < 2; ++n) {
      int co = n * 16 + (lane & 15);
      #pragma unroll
      for (int r = 0; r < 4; ++r) {
        float v = acc[m][n][r];
        int px = pxf + r;
        int row = (b * 64 + h0 + (px >> 6)) * 64 + (px & 63);
        float o;
        if (co < 18) o = v + boff[co];
        else if (co < 27) { float mm = v + bmod[co - 18]; o = 2.f / (1.f + __expf(-mm)); }
        else o = 0.f;
        om[row * 32 + co] = o;
      }
    }
  }
}

// ---------------- deformable conv: inline specs, gather-A, dbuf-B, bf16 out + stats ----------------
__global__ __launch_bounds__(256) void k_deform(const ushort* __restrict__ an,
                                                const float* __restrict__ om,
                                                const ushort* __restrict__ wB,
                                                ushort* __restrict__ ob,
                                                float* __restrict__ part) {
  __shared__ __align__(16) ushort sA[64 * 264];
  __shared__ __align__(16) ushort sB[2][256 * 40];
  const int h = blockIdx.x, b = blockIdx.y, t = threadIdx.x;
  const int lane = t & 63, wv = t >> 6;
  const int spx = t & 63, seg = t >> 6;
  f32x4 acc[4][4];
  #pragma unroll
  for (int m = 0; m < 4; ++m)
    #pragma unroll
    for (int n = 0; n < 4; ++n) acc[m][n] = (f32x4){0.f, 0.f, 0.f, 0.f};

  const ushort* base = an + (size_t)b * PLANE * 256;
  const int row = (b * 64 + h) * 64 + spx;
  uint4 bR[4];

  auto gatherA = [&](int p) {
    float dy = om[row * 32 + 2 * p];
    float dx = om[row * 32 + 2 * p + 1];
    float mk = om[row * 32 + 18 + p];
    float py = (float)(h + p / 3 - 1) + dy;
    float pxx = (float)(spx + p % 3 - 1) + dx;
    float fy = floorf(py), fx = floorf(pxx);
    float ly = py - fy, lx = pxx - fx;
    int y0 = (int)fy, x0 = (int)fx;
    bool vy0 = ((unsigned)y0 < 64u), vy1 = ((unsigned)(y0 + 1) < 64u);
    bool vx0 = ((unsigned)x0 < 64u), vx1 = ((unsigned)(x0 + 1) < 64u);
    float w00 = (1.f - ly) * (1.f - lx) * mk * ((vy0 && vx0) ? 1.f : 0.f);
    float w01 = (1.f - ly) * lx * mk * ((vy0 && vx1) ? 1.f : 0.f);
    float w10 = ly * (1.f - lx) * mk * ((vy1 && vx0) ? 1.f : 0.f);
    float w11 = ly * lx * mk * ((vy1 && vx1) ? 1.f : 0.f);
    int y0c = min(max(y0, 0), 63), y1c = min(max(y0 + 1, 0), 63);
    int x0c = min(max(x0, 0), 63), x1c = min(max(x0 + 1, 0), 63);
    const ushort* r00 = base + (y0c * 64 + x0c) * 256 + seg * 64;
    const ushort* r01 = base + (y0c * 64 + x1c) * 256 + seg * 64;
    const ushort* r10 = base + (y1c * 64 + x0c) * 256 + seg * 64;
    const ushort* r11 = base + (y1c * 64 + x1c) * 256 + seg * 64;
    #pragma unroll
    for (int j = 0; j < 8; ++j) {
      uint4 c00 = *(const uint4*)(r00 + j * 8);
      uint4 c01 = *(const uint4*)(r01 + j * 8);
      uint4 c10 = *(const uint4*)(r10 + j * 8);
      uint4 c11 = *(const uint4*)(r11 + j * 8);
      uint ou[4];
      #pragma unroll
      for (int q = 0; q < 4; ++q) {
        uint a0 = ((const uint*)&c00)[q], a1 = ((const uint*)&c01)[q];
        uint a2 = ((const uint*)&c10)[q], a3 = ((const uint*)&c11)[q];
        float lo = w00 * __uint_as_float(a0 << 16) + w01 * __uint_as_float(a1 << 16)
                 + w10 * __uint_as_float(a2 << 16) + w11 * __uint_as_float(a3 << 16);
        float hi = w00 * __uint_as_float(a0 & 0xffff0000u) + w01 * __uint_as_float(a1 & 0xffff0000u)
                 + w10 * __uint_as_float(a2 & 0xffff0000u) + w11 * __uint_as_float(a3 & 0xffff0000u);
        ou[q] = (uint)f2bf(lo) | ((uint)f2bf(hi) << 16);
      }
      *(uint4*)&sA[spx * 264 + seg * 64 + j * 8] = *(uint4*)ou;
    }
  };
  auto loadB = [&](int s) {
    const ushort* srcB = wB + (s * 256 + t) * 32;
    #pragma unroll
    for (int j = 0; j < 4; ++j) bR[j] = *(const uint4*)(srcB + j * 8);
  };
  auto writeB = [&](int buf) {
    #pragma unroll
    for (int j = 0; j < 4; ++j)
      *(uint4*)&sB[buf][t * 40 + j * 8] = bR[j];
  };

  gatherA(0);
  loadB(0); writeB(0);
  __syncthreads();
  int buf = 0;
  for (int p = 0; p < 9; ++p) {
    #pragma unroll
    for (int cic = 0; cic < 8; ++cic) {
      const int s = p * 8 + cic;
      const bool last = (s == 71);
      const bool tapEnd = (cic == 7) && (p < 8);
      if (!last) loadB(s + 1);
      const int krow = lane >> 4;
      bf16x8 af[4], bfr[4];
      #pragma unroll
      for (int m = 0; m < 4; ++m) {
        frag_cv cv;
        cv.u = *(const uint4*)&sA[(m * 16 + (lane & 15)) * 264 + cic * 32 + krow * 8];
        af[m] = cv.v;
      }
      #pragma unroll
      for (int n = 0; n < 4; ++n) {
        frag_cv cv;
        cv.u = *(const uint4*)&sB[buf][(wv * 64 + n * 16 + (lane & 15)) * 40 + krow * 8];
        bfr[n] = cv.v;
      }
      #pragma unroll
      for (int m = 0; m < 4; ++m)
        #pragma unroll
        for (int n = 0; n < 4; ++n)
          acc[m][n] = __builtin_amdgcn_mfma_f32_16x16x32_bf16(af[m], bfr[n], acc[m][n], 0, 0, 0);
      if (!last) writeB(buf ^ 1);
      __syncthreads();
      buf ^= 1;
      if (tapEnd) { gatherA(p + 1); __syncthreads(); }
    }
  }
  const int row0 = (b * 64 + h) * 64;
  #pragma unroll
  for (int m = 0; m < 4; ++m) {
    int pxo = m * 16 + (lane >> 4) * 4;
    #pragma unroll
    for (int n = 0; n < 4; ++n) {
      int co = wv * 64 + n * 16 + (lane & 15);
      #pragma unroll
      for (int r = 0; r < 4; ++r)
        ob[(row0 + pxo + r) * 256 + co] = f2bf(acc[m][n][r]);
    }
  }
  const int blk = b * 64 + h;
  #pragma unroll
  for (int n = 0; n < 4; ++n) {
    float s1 = 0.f, s2 = 0.f;
    #pragma unroll
    for (int m = 0; m < 4; ++m)
      #pragma unroll
      for (int r = 0; r < 4; ++r) {
        float v = acc[m][n][r];
        s1 += v; s2 += v * v;
      }
    s1 += __shfl_xor(s1, 16); s1 += __shfl_xor(s1, 32);
    s2 += __shfl_xor(s2, 16); s2 += __shfl_xor(s2, 32);
    if (lane < 16) {
      int co = wv * 64 + n * 16 + lane;
      part[blk * 512 + co] = s1;
      part[blk * 512 + 256 + co] = s2;
    }
  }
}

// ---------------- BN stats final reduce ----------------
template<int R>
__global__ void k_statB(const float* __restrict__ part, const float* __restrict__ g,
                        const float* __restrict__ bt, float* __restrict__ scale,
                        float* __restrict__ shift) {
  const int c = threadIdx.x;
  float s1 = 0.f, s2 = 0.f;
  for (int r = 0; r < R; ++r) { s1 += part[r * 512 + c]; s2 += part[r * 512 + 256 + c]; }
  const float inv = 1.f / 32768.f;
  float m = s1 * inv;
  float var = s2 * inv - m * m;
  float a = g[c] * rsqrtf(var + 1e-5f);
  scale[c] = a;
  shift[c] = bt[c] - m * a;
}

// ---------------- BN+ReLU: t1 bf16 NHWC -> out1 bf16 NHWC ----------------
__global__ void k_bnrelu(const ushort* __restrict__ t, const float* __restrict__ scale,
                         const float* __restrict__ shift, ushort* __restrict__ o) {
  int stride = gridDim.x * blockDim.x;
  for (int i = blockIdx.x * blockDim.x + threadIdx.x; i < 8388608 / 8; i += stride) {
    uint4 v = ((const uint4*)t)[i];
    int c0 = (i & 31) * 8;
    float4 sa = *(const float4*)&scale[c0];
    float4 sb = *(const float4*)&scale[c0 + 4];
    float4 ha = *(const float4*)&shift[c0];
    float4 hb = *(const float4*)&shift[c0 + 4];
    float e0 = __uint_as_float(v.x << 16), e1 = __uint_as_float(v.x & 0xffff0000u);
    float e2 = __uint_as_float(v.y << 16), e3 = __uint_as_float(v.y & 0xffff0000u);
    float e4 = __uint_as_float(v.z << 16), e5 = __uint_as_float(v.z & 0xffff0000u);
    float e6 = __uint_as_float(v.w << 16), e7 = __uint_as_float(v.w & 0xffff0000u);
    float q0 = fmaxf(e0 * sa.x + ha.x, 0.f), q1 = fmaxf(e1 * sa.y + ha.y, 0.f);
    float q2 = fmaxf(e2 * sa.z + ha.z, 0.f), q3 = fmaxf(e3 * sa.w + ha.w, 0.f);
    float q4 = fmaxf(e4 * sb.x + hb.x, 0.f), q5 = fmaxf(e5 * sb.y + hb.y, 0.f);
    float q6 = fmaxf(e6 * sb.z + hb.z, 0.f), q7 = fmaxf(e7 * sb.w + hb.w, 0.f);
    uint4 ou;
    ou.x = (uint)f2bf(q0) | ((uint)f2bf(q1) << 16);
    ou.y = (uint)f2bf(q2) | ((uint)f2bf(q3) << 16);
    ou.z = (uint)f2bf(q4) | ((uint)f2bf(q5) << 16);
    ou.w = (uint)f2bf(q6) | ((uint)f2bf(q7) << 16);
    ((uint4*)o)[i] = ou;
  }
}

// ---------------- final: relu(bn2(t2)+bn3(res)), bf16 NHWC -> fp32 NCHW ----------------
__global__ __launch_bounds__(256) void k_final(const ushort* __restrict__ t2, const ushort* __restrict__ res,
                                               const float* __restrict__ s2p, const float* __restrict__ sh2p,
                                               const float* __restrict__ s3p, const float* __restrict__ sh3p,
                                               float* __restrict__ o) {
  __shared__ __align__(16) float sT[64 * 68];
  const int h = blockIdx.x, b = blockIdx.y, t = threadIdx.x;
  const int row0 = (b * 64 + h) * 64;
  for (int chunk = 0; chunk < 4; ++chunk) {
    const int c0 = chunk * 64;
    {
      int px = t >> 2, s4 = t & 3;
      int cl = s4 * 16;
      int rbase = (row0 + px) * 256 + c0 + cl;
      uint4 a0 = *(const uint4*)&t2[rbase];
      uint4 a1 = *(const uint4*)&t2[rbase + 8];
      uint4 r0 = *(const uint4*)&res[rbase];
      uint4 r1 = *(const uint4*)&res[rbase + 8];
      float sav[16], shv[16], sbv[16], hbv[16];
      #pragma unroll
      for (int k = 0; k < 4; ++k) {
        float4 x1 = *(const float4*)&s2p[c0 + cl + k * 4];
        float4 x2 = *(const float4*)&sh2p[c0 + cl + k * 4];
        float4 x3 = *(const float4*)&s3p[c0 + cl + k * 4];
        float4 x4 = *(const float4*)&sh3p[c0 + cl + k * 4];
        sav[k*4]=x1.x; sav[k*4+1]=x1.y; sav[k*4+2]=x1.z; sav[k*4+3]=x1.w;
        shv[k*4]=x2.x; shv[k*4+1]=x2.y; shv[k*4+2]=x2.z; shv[k*4+3]=x2.w;
        sbv[k*4]=x3.x; sbv[k*4+1]=x3.y; sbv[k*4+2]=x3.z; sbv[k*4+3]=x3.w;
        hbv[k*4]=x4.x; hbv[k*4+1]=x4.y; hbv[k*4+2]=x4.z; hbv[k*4+3]=x4.w;
      }
      const uint* au = (const uint*)&a0;
      const uint* ru = (const uint*)&r0;
      #pragma unroll
      for (int q = 0; q < 8; ++q) {
        uint ua = (q < 4) ? au[q] : ((const uint*)&a1)[q - 4];
        uint ur = (q < 4) ? ru[q] : ((const uint*)&r1)[q - 4];
        float ae = __uint_as_float(ua << 16), ao = __uint_as_float(ua & 0xffff0000u);
        float re = __uint_as_float(ur << 16), ro = __uint_as_float(ur & 0xffff0000u);
        int ce = 2 * q, codd = 2 * q + 1;
        sT[(cl + ce) * 68 + px] = fmaxf(ae * sav[ce] + shv[ce] + re * sbv[ce] + hbv[ce], 0.f);
        sT[(cl + codd) * 68 + px] = fmaxf(ao * sav[codd] + shv[codd] + ro * sbv[codd] + hbv[codd], 0.f);
      }
    }
    __syncthreads();
    {
      int cl = t & 63, wseg = t >> 6;
      int obase = ((b * 256 + c0 + cl) * 64 + h) * 64 + wseg * 16;
      #pragma unroll
      for (int j = 0; j < 4; ++j) {
        float4 q;
        q.x = sT[cl * 68 + wseg * 16 + j * 4 + 0];
        q.y = sT[cl * 68 + wseg * 16 + j * 4 + 1];
        q.z = sT[cl * 68 + wseg * 16 + j * 4 + 2];
        q.w = sT[cl * 68 + wseg * 16 + j * 4 + 3];
        *(float4*)&o[obase + j * 4] = q;
      }
    }
    __syncthreads();
  }
}

extern "C" void kernel_launch(void* const* d_in, const int* in_sizes, int n_in,
                              void* d_out, int out_size, void* d_ws, size_t ws_size,
                              hipStream_t stream) {
  const float* x    = (const float*)d_in[0];
  const float* w1   = (const float*)d_in[2];
  const float* g1   = (const float*)d_in[4];
  const float* bt1  = (const float*)d_in[5];
  const float* woff = (const float*)d_in[6];
  const float* boff = (const float*)d_in[7];
  const float* wmod = (const float*)d_in[8];
  const float* bmod = (const float*)d_in[9];
  const float* wd   = (const float*)d_in[10];
  const float* g2   = (const float*)d_in[12];
  const float* bt2  = (const float*)d_in[13];
  const float* wds  = (const float*)d_in[14];
  const float* g3   = (const float*)d_in[16];
  const float* bt3  = (const float*)d_in[17];

  float* ws = (float*)d_ws;
  ushort* wb1   = (ushort*)ws;                   // 294912 f32
  ushort* wbd   = (ushort*)(ws + 294912);        // 294912
  ushort* wbom  = (ushort*)(ws + 589824);        // 36864
  ushort* wbds  = (ushort*)(ws + 626688);        // 32768
  float*  SC    = ws + 659456;                   // 2048
  float*  part1 = ws + 661504;                   // 262144
  float*  part2 = ws + 923648;                   // 262144
  float*  part3 = ws + 1185792;                  // 262144
  ushort* xn    = (ushort*)(ws + 1447936);       // 4194304
  ushort* out1  = (ushort*)(ws + 5642240);       // 4194304
  ushort* t1b   = (ushort*)(ws + 9836544);       // 4194304
  ushort* t2b   = (ushort*)(ws + 14030848);      // 4194304
  ushort* resb  = (ushort*)(ws + 18225152);      // 4194304
  float*  om    = ws + 22419456;                 // 1048576 (end 23468032 f32 = 94 MB)

  dim3 ghb(64, 8);
  k_prep<<<512, 256, 0, stream>>>(w1, wd, woff, wmod, wds, wb1, wbd, wbom, wbds);
  k_x2nhwc<<<ghb, 256, 0, stream>>>(x, xn);
  k_convbig<9><<<ghb, 256, 0, stream>>>(xn, wb1, t1b, part1);
  k_statB<512><<<1, 256, 0, stream>>>(part1, g1, bt1, SC, SC + 256);
  k_bnrelu<<<2048, 256, 0, stream>>>(t1b, SC, SC + 256, out1);
  k_convom<<<dim3(32, 8), 256, 0, stream>>>(out1, wbom, boff, bmod, om);
  k_deform<<<ghb, 256, 0, stream>>>(out1, om, wbd, t2b, part2);
  k_statB<512><<<1, 256, 0, stream>>>(part2, g2, bt2, SC + 512, SC + 768);
  k_convbig<1><<<ghb, 256, 0, stream>>>(xn, wbds, resb, part3);
  k_statB<512><<<1, 256, 0, stream>>>(part3, g3, bt3, SC + 1024, SC + 1280);
  k_final<<<ghb, 256, 0, stream>>>(t2b, resb, SC + 512, SC + 768, SC + 1024, SC + 1280, (float*)d_out);
}

// Round 7
// 613.676 us; speedup vs baseline: 1.1519x; 1.1519x over previous
//
#include <hip/hip_runtime.h>
#include <hip/hip_fp16.h>
#include <math.h>

typedef __attribute__((ext_vector_type(8))) _Float16 f16x8;
typedef __attribute__((ext_vector_type(4))) float f32x4;

#define PLANE 4096

__device__ inline ushort f2h(float f) { return __half_as_ushort(__float2half_rn(f)); }
__device__ inline __half2 u2h2(uint u) { union { uint u; __half2 h; } x; x.u = u; return x.h; }
__device__ inline uint h22u(__half2 h) { union { uint u; __half2 h; } x; x.h = h; return x.u; }

union frag_u { uint4 u; f16x8 v; };

// ---------------- weight prep: fp32 -> fp16 [s=(p,cic)][co][kk] ----------------
__global__ void k_prep(const float* __restrict__ w1, const float* __restrict__ wd,
                       const float* __restrict__ woff, const float* __restrict__ wmod,
                       const float* __restrict__ wds,
                       ushort* __restrict__ wb1, ushort* __restrict__ wbd,
                       ushort* __restrict__ wbom, ushort* __restrict__ wbds) {
  int stride = gridDim.x * blockDim.x;
  int t0 = blockIdx.x * blockDim.x + threadIdx.x;
  for (int s = t0; s < 9 * 8 * 256 * 32; s += stride) {
    int kk = s & 31, co = (s >> 5) & 255, cic = (s >> 13) & 7, p = s >> 16;
    int ci = cic * 32 + kk;
    wb1[s] = f2h(w1[(co * 256 + ci) * 9 + p]);
    wbd[s] = f2h(wd[(co * 256 + ci) * 9 + p]);
  }
  for (int s = t0; s < 9 * 8 * 32 * 32; s += stride) {
    int kk = s & 31, co = (s >> 5) & 31, cic = (s >> 10) & 7, p = s >> 13;
    int ci = cic * 32 + kk;
    float v = 0.f;
    if (co < 18) v = woff[(co * 256 + ci) * 9 + p];
    else if (co < 27) v = wmod[((co - 18) * 256 + ci) * 9 + p];
    wbom[s] = f2h(v);
  }
  for (int s = t0; s < 8 * 256 * 32; s += stride) {
    int kk = s & 31, co = (s >> 5) & 255, cic = s >> 13;
    wbds[s] = f2h(wds[co * 256 + cic * 32 + kk]);
  }
}

// ---------------- x NCHW fp32 -> xn NHWC fp16 ----------------
__global__ __launch_bounds__(256) void k_x2nhwc(const float* __restrict__ x,
                                                ushort* __restrict__ xn) {
  __shared__ __align__(16) float sT[64 * 68];
  const int h = blockIdx.x, b = blockIdx.y, t = threadIdx.x;
  for (int chunk = 0; chunk < 4; ++chunk) {
    const int c0 = chunk * 64;
    {
      int w4 = (t & 15) * 4, cl = t >> 4;
      #pragma unroll
      for (int i = 0; i < 4; ++i) {
        int c = cl * 4 + i;
        float4 v = *(const float4*)&x[((b * 256 + c0 + c) * 64 + h) * 64 + w4];
        *(float4*)&sT[c * 68 + w4] = v;
      }
    }
    __syncthreads();
    {
      int w = t & 63, cg = t >> 6;
      #pragma unroll
      for (int i = 0; i < 2; ++i) {
        int cg2 = cg * 2 + i;
        uint ou[4];
        #pragma unroll
        for (int k2 = 0; k2 < 4; ++k2) {
          float lo = sT[(cg2 * 8 + k2 * 2) * 68 + w];
          float hi = sT[(cg2 * 8 + k2 * 2 + 1) * 68 + w];
          ou[k2] = (uint)f2h(lo) | ((uint)f2h(hi) << 16);
        }
        *(uint4*)&xn[(((b * 64 + h) * 64 + w) * 256) + c0 + cg2 * 8] = *(uint4*)ou;
      }
    }
    __syncthreads();
  }
}

// ---------------- big conv (3x3 pad1 / 1x1): global-B frags, swizzled sA, fp16 ----------------
// grid (64,8); 4 waves; wave wv owns co [wv*64,+64), all 64 px. Barriers only at tap staging.
template<int NTAP>
__global__ __launch_bounds__(256, 4) void k_convbig(const ushort* __restrict__ an,
                                                    const ushort* __restrict__ wB,
                                                    ushort* __restrict__ ob,
                                                    float* __restrict__ part) {
  __shared__ __align__(16) ushort sA[64 * 256];
  const int h = blockIdx.x, b = blockIdx.y, t = threadIdx.x;
  const int lane = t & 63, wv = t >> 6;
  const int cow = wv * 64;
  const int krow = lane >> 4;
  f32x4 acc[4][4];
  #pragma unroll
  for (int m = 0; m < 4; ++m)
    #pragma unroll
    for (int n = 0; n < 4; ++n) acc[m][n] = (f32x4){0.f, 0.f, 0.f, 0.f};

  const int chunk = t & 31, pr = t >> 5;
  for (int p = 0; p < NTAP; ++p) {
    if (p) __syncthreads();
    {
      int ky = (NTAP == 9) ? p / 3 : 1, kx = (NTAP == 9) ? p % 3 : 1;
      int y = h + ky - 1;
      bool oky = ((unsigned)y < 64u);
      #pragma unroll
      for (int j = 0; j < 8; ++j) {
        int px = j * 8 + pr;
        int sx = px + kx - 1;
        bool ok = oky && ((unsigned)sx < 64u);
        uint4 v = {0u, 0u, 0u, 0u};
        if (ok) v = *(const uint4*)(an + (((b * 64 + y) * 64 + sx) * 256) + chunk * 8);
        *(uint4*)&sA[px * 256 + ((chunk ^ (px & 7)) * 8)] = v;
      }
    }
    __syncthreads();
    #pragma unroll
    for (int cic = 0; cic < 8; ++cic) {
      const int s = p * 8 + cic;
      frag_u bu[4], au[4];
      #pragma unroll
      for (int n = 0; n < 4; ++n)
        bu[n].u = *(const uint4*)(wB + ((s * 256 + cow + n * 16 + (lane & 15)) * 32) + krow * 8);
      #pragma unroll
      for (int m = 0; m < 4; ++m)
        au[m].u = *(const uint4*)&sA[(m * 16 + (lane & 15)) * 256 + (((cic * 4 + krow) ^ (lane & 7)) * 8)];
      #pragma unroll
      for (int m = 0; m < 4; ++m)
        #pragma unroll
        for (int n = 0; n < 4; ++n)
          acc[m][n] = __builtin_amdgcn_mfma_f32_16x16x32_f16(au[m].v, bu[n].v, acc[m][n], 0, 0, 0);
    }
  }
  // ---- BN partials from fp32 acc
  const int blk = b * 64 + h;
  #pragma unroll
  for (int n = 0; n < 4; ++n) {
    float s1 = 0.f, s2 = 0.f;
    #pragma unroll
    for (int m = 0; m < 4; ++m)
      #pragma unroll
      for (int r = 0; r < 4; ++r) { float v = acc[m][n][r]; s1 += v; s2 += v * v; }
    s1 += __shfl_xor(s1, 16); s1 += __shfl_xor(s1, 32);
    s2 += __shfl_xor(s2, 16); s2 += __shfl_xor(s2, 32);
    if (lane < 16) {
      int co = cow + n * 16 + lane;
      part[co * 512 + blk] = s1;
      part[131072 + co * 512 + blk] = s2;
    }
  }
  // ---- coalesced fp16 store via LDS transpose
  __syncthreads();
  #pragma unroll
  for (int m = 0; m < 4; ++m) {
    int pxo = m * 16 + (lane >> 4) * 4;
    #pragma unroll
    for (int n = 0; n < 4; ++n) {
      int co = cow + n * 16 + (lane & 15);
      #pragma unroll
      for (int r = 0; r < 4; ++r)
        sA[(pxo + r) * 256 + co] = f2h(acc[m][n][r]);
    }
  }
  __syncthreads();
  const size_t row0 = (size_t)(b * 64 + h) * 64;
  #pragma unroll
  for (int j = 0; j < 8; ++j) {
    int px = j * 8 + pr;
    *(uint4*)&ob[(row0 + px) * 256 + chunk * 8] = *(const uint4*)&sA[px * 256 + chunk * 8];
  }
}

// ---------------- offset/mask conv: M=32, grid (128,8), global-B frags ----------------
__global__ __launch_bounds__(256, 4) void k_convom(const ushort* __restrict__ an,
                                                   const ushort* __restrict__ wB,
                                                   const float* __restrict__ boff,
                                                   const float* __restrict__ bmod,
                                                   float* __restrict__ om) {
  __shared__ __align__(16) ushort sA[32 * 256];
  const int h = blockIdx.x >> 1, ph = (blockIdx.x & 1) * 32, b = blockIdx.y, t = threadIdx.x;
  const int lane = t & 63, wv = t >> 6;
  const int mloc = wv & 1, nt = wv >> 1;
  const int krow = lane >> 4;
  f32x4 acc = (f32x4){0.f, 0.f, 0.f, 0.f};
  const int chunk = t & 31, pr = t >> 5;
  for (int p = 0; p < 9; ++p) {
    if (p) __syncthreads();
    {
      int ky = p / 3, kx = p % 3;
      int y = h + ky - 1;
      bool oky = ((unsigned)y < 64u);
      #pragma unroll
      for (int j = 0; j < 4; ++j) {
        int lpx = j * 8 + pr;
        int sx = ph + lpx + kx - 1;
        bool ok = oky && ((unsigned)sx < 64u);
        uint4 v = {0u, 0u, 0u, 0u};
        if (ok) v = *(const uint4*)(an + (((b * 64 + y) * 64 + sx) * 256) + chunk * 8);
        *(uint4*)&sA[lpx * 256 + ((chunk ^ (lpx & 7)) * 8)] = v;
      }
    }
    __syncthreads();
    #pragma unroll
    for (int cic = 0; cic < 8; ++cic) {
      const int s = p * 8 + cic;
      frag_u bu, au;
      bu.u = *(const uint4*)(wB + ((s * 32 + nt * 16 + (lane & 15)) * 32) + krow * 8);
      int lpx = mloc * 16 + (lane & 15);
      au.u = *(const uint4*)&sA[lpx * 256 + (((cic * 4 + krow) ^ (lpx & 7)) * 8)];
      acc = __builtin_amdgcn_mfma_f32_16x16x32_f16(au.v, bu.v, acc, 0, 0, 0);
    }
  }
  int co = nt * 16 + (lane & 15);
  #pragma unroll
  for (int r = 0; r < 4; ++r) {
    int px = ph + mloc * 16 + (lane >> 4) * 4 + r;
    int row = (b * 64 + h) * 64 + px;
    float v = acc[r];
    float o;
    if (co < 18) o = v + boff[co];
    else if (co < 27) { float mm = v + bmod[co - 18]; o = 2.f / (1.f + __expf(-mm)); }
    else o = 0.f;
    om[row * 32 + co] = o;
  }
}

// ---------------- deformable conv: pk_fma gather, global-B frags, swizzled sA ----------------
__global__ __launch_bounds__(256, 4) void k_deform(const ushort* __restrict__ an,
                                                   const float* __restrict__ om,
                                                   const ushort* __restrict__ wB,
                                                   ushort* __restrict__ ob,
                                                   float* __restrict__ part) {
  __shared__ __align__(16) ushort sA[64 * 256];
  const int h = blockIdx.x, b = blockIdx.y, t = threadIdx.x;
  const int lane = t & 63, wv = t >> 6;
  const int cow = wv * 64;
  const int krow = lane >> 4;
  const int spx = t & 63, seg = t >> 6;
  f32x4 acc[4][4];
  #pragma unroll
  for (int m = 0; m < 4; ++m)
    #pragma unroll
    for (int n = 0; n < 4; ++n) acc[m][n] = (f32x4){0.f, 0.f, 0.f, 0.f};

  const ushort* base = an + (size_t)b * PLANE * 256;
  const int row = (b * 64 + h) * 64 + spx;

  for (int p = 0; p < 9; ++p) {
    if (p) __syncthreads();
    {
      float dy = om[row * 32 + 2 * p];
      float dx = om[row * 32 + 2 * p + 1];
      float mk = om[row * 32 + 18 + p];
      float py = (float)(h + p / 3 - 1) + dy;
      float pxx = (float)(spx + p % 3 - 1) + dx;
      float fy = floorf(py), fx = floorf(pxx);
      float ly = py - fy, lx = pxx - fx;
      int y0 = (int)fy, x0 = (int)fx;
      bool vy0 = ((unsigned)y0 < 64u), vy1 = ((unsigned)(y0 + 1) < 64u);
      bool vx0 = ((unsigned)x0 < 64u), vx1 = ((unsigned)(x0 + 1) < 64u);
      float w00 = (1.f - ly) * (1.f - lx) * mk * ((vy0 && vx0) ? 1.f : 0.f);
      float w01 = (1.f - ly) * lx * mk * ((vy0 && vx1) ? 1.f : 0.f);
      float w10 = ly * (1.f - lx) * mk * ((vy1 && vx0) ? 1.f : 0.f);
      float w11 = ly * lx * mk * ((vy1 && vx1) ? 1.f : 0.f);
      __half2 w00h = __float2half2_rn(w00), w01h = __float2half2_rn(w01);
      __half2 w10h = __float2half2_rn(w10), w11h = __float2half2_rn(w11);
      int y0c = min(max(y0, 0), 63), y1c = min(max(y0 + 1, 0), 63);
      int x0c = min(max(x0, 0), 63), x1c = min(max(x0 + 1, 0), 63);
      const ushort* r00 = base + (y0c * 64 + x0c) * 256 + seg * 64;
      const ushort* r01 = base + (y0c * 64 + x1c) * 256 + seg * 64;
      const ushort* r10 = base + (y1c * 64 + x0c) * 256 + seg * 64;
      const ushort* r11 = base + (y1c * 64 + x1c) * 256 + seg * 64;
      #pragma unroll
      for (int j = 0; j < 8; ++j) {
        uint4 c00 = *(const uint4*)(r00 + j * 8);
        uint4 c01 = *(const uint4*)(r01 + j * 8);
        uint4 c10 = *(const uint4*)(r10 + j * 8);
        uint4 c11 = *(const uint4*)(r11 + j * 8);
        uint ou[4];
        #pragma unroll
        for (int q = 0; q < 4; ++q) {
          __half2 r2 = __hmul2(u2h2(((const uint*)&c00)[q]), w00h);
          r2 = __hfma2(u2h2(((const uint*)&c01)[q]), w01h, r2);
          r2 = __hfma2(u2h2(((const uint*)&c10)[q]), w10h, r2);
          r2 = __hfma2(u2h2(((const uint*)&c11)[q]), w11h, r2);
          ou[q] = h22u(r2);
        }
        *(uint4*)&sA[spx * 256 + seg * 64 + ((j ^ (spx & 7)) * 8)] = *(uint4*)ou;
      }
    }
    __syncthreads();
    #pragma unroll
    for (int cic = 0; cic < 8; ++cic) {
      const int s = p * 8 + cic;
      frag_u bu[4], au[4];
      #pragma unroll
      for (int n = 0; n < 4; ++n)
        bu[n].u = *(const uint4*)(wB + ((s * 256 + cow + n * 16 + (lane & 15)) * 32) + krow * 8);
      #pragma unroll
      for (int m = 0; m < 4; ++m)
        au[m].u = *(const uint4*)&sA[(m * 16 + (lane & 15)) * 256 + (((cic * 4 + krow) ^ (lane & 7)) * 8)];
      #pragma unroll
      for (int m = 0; m < 4; ++m)
        #pragma unroll
        for (int n = 0; n < 4; ++n)
          acc[m][n] = __builtin_amdgcn_mfma_f32_16x16x32_f16(au[m].v, bu[n].v, acc[m][n], 0, 0, 0);
    }
  }
  const int blk = b * 64 + h;
  #pragma unroll
  for (int n = 0; n < 4; ++n) {
    float s1 = 0.f, s2 = 0.f;
    #pragma unroll
    for (int m = 0; m < 4; ++m)
      #pragma unroll
      for (int r = 0; r < 4; ++r) { float v = acc[m][n][r]; s1 += v; s2 += v * v; }
    s1 += __shfl_xor(s1, 16); s1 += __shfl_xor(s1, 32);
    s2 += __shfl_xor(s2, 16); s2 += __shfl_xor(s2, 32);
    if (lane < 16) {
      int co = cow + n * 16 + lane;
      part[co * 512 + blk] = s1;
      part[131072 + co * 512 + blk] = s2;
    }
  }
  __syncthreads();
  #pragma unroll
  for (int m = 0; m < 4; ++m) {
    int pxo = m * 16 + (lane >> 4) * 4;
    #pragma unroll
    for (int n = 0; n < 4; ++n) {
      int co = cow + n * 16 + (lane & 15);
      #pragma unroll
      for (int r = 0; r < 4; ++r)
        sA[(pxo + r) * 256 + co] = f2h(acc[m][n][r]);
    }
  }
  __syncthreads();
  const size_t row0 = (size_t)(b * 64 + h) * 64;
  const int chunk = t & 31, pr = t >> 5;
  #pragma unroll
  for (int j = 0; j < 8; ++j) {
    int px = j * 8 + pr;
    *(uint4*)&ob[(row0 + px) * 256 + chunk * 8] = *(const uint4*)&sA[px * 256 + chunk * 8];
  }
}

// ---------------- BN stats final reduce (part transposed: [2][256][512]) ----------------
__global__ void k_statB(const float* __restrict__ part, const float* __restrict__ g,
                        const float* __restrict__ bt, float* __restrict__ scale,
                        float* __restrict__ shift) {
  __shared__ float s2buf[256];
  const int tid = threadIdx.x;
  const int c = tid & 255, which = tid >> 8;
  const float4* p4 = (const float4*)(part + which * 131072 + c * 512);
  float s = 0.f;
  for (int r = 0; r < 128; ++r) { float4 v = p4[r]; s += v.x + v.y + v.z + v.w; }
  if (which) s2buf[c] = s;
  __syncthreads();
  if (!which) {
    const float inv = 1.f / 32768.f;
    float m = s * inv;
    float var = s2buf[c] * inv - m * m;
    float a = g[c] * rsqrtf(var + 1e-5f);
    scale[c] = a;
    shift[c] = bt[c] - m * a;
  }
}

// ---------------- BN+ReLU: t1 fp16 NHWC -> out1 fp16 NHWC ----------------
__global__ void k_bnrelu(const ushort* __restrict__ t, const float* __restrict__ scale,
                         const float* __restrict__ shift, ushort* __restrict__ o) {
  int stride = gridDim.x * blockDim.x;
  for (int i = blockIdx.x * blockDim.x + threadIdx.x; i < 8388608 / 8; i += stride) {
    uint4 v = ((const uint4*)t)[i];
    int c0 = (i & 31) * 8;
    uint ou[4];
    #pragma unroll
    for (int q = 0; q < 4; ++q) {
      float2 f = __half22float2(u2h2(((const uint*)&v)[q]));
      float sa = scale[c0 + 2 * q], sb = scale[c0 + 2 * q + 1];
      float ha = shift[c0 + 2 * q], hb = shift[c0 + 2 * q + 1];
      float qa = fmaxf(f.x * sa + ha, 0.f);
      float qb = fmaxf(f.y * sb + hb, 0.f);
      ou[q] = (uint)f2h(qa) | ((uint)f2h(qb) << 16);
    }
    ((uint4*)o)[i] = *(uint4*)ou;
  }
}

// ---------------- final: relu(bn2(t2)+bn3(res)), fp16 NHWC -> fp32 NCHW ----------------
__global__ __launch_bounds__(256) void k_final(const ushort* __restrict__ t2, const ushort* __restrict__ res,
                                               const float* __restrict__ s2p, const float* __restrict__ sh2p,
                                               const float* __restrict__ s3p, const float* __restrict__ sh3p,
                                               float* __restrict__ o) {
  __shared__ __align__(16) float sT[64 * 68];
  const int h = blockIdx.x, b = blockIdx.y, t = threadIdx.x;
  const int row0 = (b * 64 + h) * 64;
  for (int chunk = 0; chunk < 4; ++chunk) {
    const int c0 = chunk * 64;
    {
      int px = t >> 2, s4 = t & 3;
      int cl = s4 * 16;
      int rbase = (row0 + px) * 256 + c0 + cl;
      uint4 a0 = *(const uint4*)&t2[rbase];
      uint4 a1 = *(const uint4*)&t2[rbase + 8];
      uint4 r0 = *(const uint4*)&res[rbase];
      uint4 r1 = *(const uint4*)&res[rbase + 8];
      #pragma unroll
      for (int q = 0; q < 8; ++q) {
        uint ua = (q < 4) ? ((const uint*)&a0)[q] : ((const uint*)&a1)[q - 4];
        uint ur = (q < 4) ? ((const uint*)&r0)[q] : ((const uint*)&r1)[q - 4];
        float2 fa = __half22float2(u2h2(ua));
        float2 fr = __half22float2(u2h2(ur));
        int ce = cl + 2 * q, codd = ce + 1;
        sT[ce * 68 + px] = fmaxf(fa.x * s2p[c0 + ce] + sh2p[c0 + ce] + fr.x * s3p[c0 + ce] + sh3p[c0 + ce], 0.f);
        sT[codd * 68 + px] = fmaxf(fa.y * s2p[c0 + codd] + sh2p[c0 + codd] + fr.y * s3p[c0 + codd] + sh3p[c0 + codd], 0.f);
      }
    }
    __syncthreads();
    {
      int cl = t & 63, wseg = t >> 6;
      int obase = ((b * 256 + c0 + cl) * 64 + h) * 64 + wseg * 16;
      #pragma unroll
      for (int j = 0; j < 4; ++j) {
        float4 q;
        q.x = sT[cl * 68 + wseg * 16 + j * 4 + 0];
        q.y = sT[cl * 68 + wseg * 16 + j * 4 + 1];
        q.z = sT[cl * 68 + wseg * 16 + j * 4 + 2];
        q.w = sT[cl * 68 + wseg * 16 + j * 4 + 3];
        *(float4*)&o[obase + j * 4] = q;
      }
    }
    __syncthreads();
  }
}

extern "C" void kernel_launch(void* const* d_in, const int* in_sizes, int n_in,
                              void* d_out, int out_size, void* d_ws, size_t ws_size,
                              hipStream_t stream) {
  const float* x    = (const float*)d_in[0];
  const float* w1   = (const float*)d_in[2];
  const float* g1   = (const float*)d_in[4];
  const float* bt1  = (const float*)d_in[5];
  const float* woff = (const float*)d_in[6];
  const float* boff = (const float*)d_in[7];
  const float* wmod = (const float*)d_in[8];
  const float* bmod = (const float*)d_in[9];
  const float* wd   = (const float*)d_in[10];
  const float* g2   = (const float*)d_in[12];
  const float* bt2  = (const float*)d_in[13];
  const float* wds  = (const float*)d_in[14];
  const float* g3   = (const float*)d_in[16];
  const float* bt3  = (const float*)d_in[17];

  float* ws = (float*)d_ws;
  ushort* wb1   = (ushort*)ws;                   // 294912 f32
  ushort* wbd   = (ushort*)(ws + 294912);        // 294912
  ushort* wbom  = (ushort*)(ws + 589824);        // 36864
  ushort* wbds  = (ushort*)(ws + 626688);        // 32768
  float*  SC    = ws + 659456;                   // 2048
  float*  part1 = ws + 661504;                   // 262144
  float*  part2 = ws + 923648;                   // 262144
  float*  part3 = ws + 1185792;                  // 262144
  ushort* xn    = (ushort*)(ws + 1447936);       // 4194304
  ushort* out1  = (ushort*)(ws + 5642240);       // 4194304
  ushort* t1b   = (ushort*)(ws + 9836544);       // 4194304
  ushort* t2b   = (ushort*)(ws + 14030848);      // 4194304
  ushort* resb  = (ushort*)(ws + 18225152);      // 4194304
  float*  om    = ws + 22419456;                 // 1048576

  dim3 ghb(64, 8);
  k_prep<<<512, 256, 0, stream>>>(w1, wd, woff, wmod, wds, wb1, wbd, wbom, wbds);
  k_x2nhwc<<<ghb, 256, 0, stream>>>(x, xn);
  k_convbig<9><<<ghb, 256, 0, stream>>>(xn, wb1, t1b, part1);
  k_statB<<<1, 512, 0, stream>>>(part1, g1, bt1, SC, SC + 256);
  k_bnrelu<<<2048, 256, 0, stream>>>(t1b, SC, SC + 256, out1);
  k_convom<<<dim3(128, 8), 256, 0, stream>>>(out1, wbom, boff, bmod, om);
  k_deform<<<ghb, 256, 0, stream>>>(out1, om, wbd, t2b, part2);
  k_statB<<<1, 512, 0, stream>>>(part2, g2, bt2, SC + 512, SC + 768);
  k_convbig<1><<<ghb, 256, 0, stream>>>(xn, wbds, resb, part3);
  k_statB<<<1, 512, 0, stream>>>(part3, g3, bt3, SC + 1024, SC + 1280);
  k_final<<<ghb, 256, 0, stream>>>(t2b, resb, SC + 512, SC + 768, SC + 1024, SC + 1280, (float*)d_out);
}

// Round 8
// 449.221 us; speedup vs baseline: 1.5736x; 1.3661x over previous
//
#include <hip/hip_runtime.h>
#include <hip/hip_fp16.h>
#include <math.h>

typedef __attribute__((ext_vector_type(8))) _Float16 f16x8;
typedef __attribute__((ext_vector_type(4))) float f32x4;

#define PLANE 4096

__device__ inline ushort f2h(float f) { return __half_as_ushort(__float2half_rn(f)); }
__device__ inline __half2 u2h2(uint u) { union { uint u; __half2 h; } x; x.u = u; return x.h; }
__device__ inline uint h22u(__half2 h) { union { uint u; __half2 h; } x; x.h = h; return x.u; }

union frag_u { uint4 u; f16x8 v; };

// ---------------- weight prep: fp32 -> fp16 [s=(p,cic)][co][kk] ----------------
__global__ void k_prep(const float* __restrict__ w1, const float* __restrict__ wd,
                       const float* __restrict__ woff, const float* __restrict__ wmod,
                       const float* __restrict__ wds,
                       ushort* __restrict__ wb1, ushort* __restrict__ wbd,
                       ushort* __restrict__ wbom, ushort* __restrict__ wbds) {
  int stride = gridDim.x * blockDim.x;
  int t0 = blockIdx.x * blockDim.x + threadIdx.x;
  for (int s = t0; s < 9 * 8 * 256 * 32; s += stride) {
    int kk = s & 31, co = (s >> 5) & 255, cic = (s >> 13) & 7, p = s >> 16;
    int ci = cic * 32 + kk;
    wb1[s] = f2h(w1[(co * 256 + ci) * 9 + p]);
    wbd[s] = f2h(wd[(co * 256 + ci) * 9 + p]);
  }
  for (int s = t0; s < 9 * 8 * 32 * 32; s += stride) {
    int kk = s & 31, co = (s >> 5) & 31, cic = (s >> 10) & 7, p = s >> 13;
    int ci = cic * 32 + kk;
    float v = 0.f;
    if (co < 18) v = woff[(co * 256 + ci) * 9 + p];
    else if (co < 27) v = wmod[((co - 18) * 256 + ci) * 9 + p];
    wbom[s] = f2h(v);
  }
  for (int s = t0; s < 8 * 256 * 32; s += stride) {
    int kk = s & 31, co = (s >> 5) & 255, cic = s >> 13;
    wbds[s] = f2h(wds[co * 256 + cic * 32 + kk]);
  }
}

// ---------------- x NCHW fp32 -> xn NHWC fp16 (grid (b,h) for XCD pinning) ----------------
__global__ __launch_bounds__(256) void k_x2nhwc(const float* __restrict__ x,
                                                ushort* __restrict__ xn) {
  __shared__ __align__(16) float sT[64 * 68];
  const int b = blockIdx.x, h = blockIdx.y, t = threadIdx.x;
  for (int chunk = 0; chunk < 4; ++chunk) {
    const int c0 = chunk * 64;
    {
      int w4 = (t & 15) * 4, cl = t >> 4;
      #pragma unroll
      for (int i = 0; i < 4; ++i) {
        int c = cl * 4 + i;
        float4 v = *(const float4*)&x[((b * 256 + c0 + c) * 64 + h) * 64 + w4];
        *(float4*)&sT[c * 68 + w4] = v;
      }
    }
    __syncthreads();
    {
      int w = t & 63, cg = t >> 6;
      #pragma unroll
      for (int i = 0; i < 2; ++i) {
        int cg2 = cg * 2 + i;
        uint ou[4];
        #pragma unroll
        for (int k2 = 0; k2 < 4; ++k2) {
          float lo = sT[(cg2 * 8 + k2 * 2) * 68 + w];
          float hi = sT[(cg2 * 8 + k2 * 2 + 1) * 68 + w];
          ou[k2] = (uint)f2h(lo) | ((uint)f2h(hi) << 16);
        }
        *(uint4*)&xn[(((b * 64 + h) * 64 + w) * 256) + c0 + cg2 * 8] = *(uint4*)ou;
      }
    }
    __syncthreads();
  }
}

// ---------------- big conv (3x3 pad1 / 1x1): 512 thr, 8 waves, global-B frags ----------------
// grid (8,64) = (b,h) -> XCD = b. Wave wv owns co [wv*32,+32), all 64 px.
template<int NTAP>
__global__ __launch_bounds__(512, 4) void k_convbig(const ushort* __restrict__ an,
                                                    const ushort* __restrict__ wB,
                                                    ushort* __restrict__ ob,
                                                    float* __restrict__ part) {
  __shared__ __align__(16) ushort sA[64 * 256];
  const int b = blockIdx.x, h = blockIdx.y, t = threadIdx.x;
  const int lane = t & 63, wv = t >> 6;
  const int cow = wv * 32;
  const int krow = lane >> 4;
  f32x4 acc[4][2];
  #pragma unroll
  for (int m = 0; m < 4; ++m)
    #pragma unroll
    for (int n = 0; n < 2; ++n) acc[m][n] = (f32x4){0.f, 0.f, 0.f, 0.f};

  const int chunk = t & 31, pr = t >> 5;  // chunk: 8-ch group, pr: 0..15
  for (int p = 0; p < NTAP; ++p) {
    if (p) __syncthreads();
    {
      int ky = (NTAP == 9) ? p / 3 : 1, kx = (NTAP == 9) ? p % 3 : 1;
      int y = h + ky - 1;
      bool oky = ((unsigned)y < 64u);
      #pragma unroll
      for (int j = 0; j < 4; ++j) {
        int px = j * 16 + pr;
        int sx = px + kx - 1;
        bool ok = oky && ((unsigned)sx < 64u);
        uint4 v = {0u, 0u, 0u, 0u};
        if (ok) v = *(const uint4*)(an + (((b * 64 + y) * 64 + sx) * 256) + chunk * 8);
        *(uint4*)&sA[px * 256 + ((chunk ^ (px & 7)) * 8)] = v;
      }
    }
    __syncthreads();
    #pragma unroll
    for (int cic = 0; cic < 8; ++cic) {
      const int s = p * 8 + cic;
      frag_u bu[2], au[4];
      #pragma unroll
      for (int n = 0; n < 2; ++n)
        bu[n].u = *(const uint4*)(wB + ((s * 256 + cow + n * 16 + (lane & 15)) * 32) + krow * 8);
      #pragma unroll
      for (int m = 0; m < 4; ++m)
        au[m].u = *(const uint4*)&sA[(m * 16 + (lane & 15)) * 256 + (((cic * 4 + krow) ^ (lane & 7)) * 8)];
      #pragma unroll
      for (int m = 0; m < 4; ++m)
        #pragma unroll
        for (int n = 0; n < 2; ++n)
          acc[m][n] = __builtin_amdgcn_mfma_f32_16x16x32_f16(au[m].v, bu[n].v, acc[m][n], 0, 0, 0);
    }
  }
  // ---- BN partials from fp32 acc
  const int blk = b * 64 + h;
  #pragma unroll
  for (int n = 0; n < 2; ++n) {
    float s1 = 0.f, s2 = 0.f;
    #pragma unroll
    for (int m = 0; m < 4; ++m)
      #pragma unroll
      for (int r = 0; r < 4; ++r) { float v = acc[m][n][r]; s1 += v; s2 += v * v; }
    s1 += __shfl_xor(s1, 16); s1 += __shfl_xor(s1, 32);
    s2 += __shfl_xor(s2, 16); s2 += __shfl_xor(s2, 32);
    if (lane < 16) {
      int co = cow + n * 16 + lane;
      part[co * 512 + blk] = s1;
      part[131072 + co * 512 + blk] = s2;
    }
  }
  // ---- coalesced fp16 store via LDS transpose
  __syncthreads();
  #pragma unroll
  for (int m = 0; m < 4; ++m) {
    int pxo = m * 16 + (lane >> 4) * 4;
    #pragma unroll
    for (int n = 0; n < 2; ++n) {
      int co = cow + n * 16 + (lane & 15);
      #pragma unroll
      for (int r = 0; r < 4; ++r)
        sA[(pxo + r) * 256 + co] = f2h(acc[m][n][r]);
    }
  }
  __syncthreads();
  const size_t row0 = (size_t)(b * 64 + h) * 64;
  #pragma unroll
  for (int j = 0; j < 4; ++j) {
    int px = j * 16 + pr;
    *(uint4*)&ob[(row0 + px) * 256 + chunk * 8] = *(const uint4*)&sA[px * 256 + chunk * 8];
  }
}

// ---------------- offset/mask conv: grid (8,128) = (b, h*2+half), global-B frags ----------------
__global__ __launch_bounds__(256, 4) void k_convom(const ushort* __restrict__ an,
                                                   const ushort* __restrict__ wB,
                                                   const float* __restrict__ boff,
                                                   const float* __restrict__ bmod,
                                                   float* __restrict__ om) {
  __shared__ __align__(16) ushort sA[32 * 256];
  const int b = blockIdx.x, h = blockIdx.y >> 1, ph = (blockIdx.y & 1) * 32, t = threadIdx.x;
  const int lane = t & 63, wv = t >> 6;
  const int mloc = wv & 1, nt = wv >> 1;
  const int krow = lane >> 4;
  f32x4 acc = (f32x4){0.f, 0.f, 0.f, 0.f};
  const int chunk = t & 31, pr = t >> 5;
  for (int p = 0; p < 9; ++p) {
    if (p) __syncthreads();
    {
      int ky = p / 3, kx = p % 3;
      int y = h + ky - 1;
      bool oky = ((unsigned)y < 64u);
      #pragma unroll
      for (int j = 0; j < 4; ++j) {
        int lpx = j * 8 + pr;
        int sx = ph + lpx + kx - 1;
        bool ok = oky && ((unsigned)sx < 64u);
        uint4 v = {0u, 0u, 0u, 0u};
        if (ok) v = *(const uint4*)(an + (((b * 64 + y) * 64 + sx) * 256) + chunk * 8);
        *(uint4*)&sA[lpx * 256 + ((chunk ^ (lpx & 7)) * 8)] = v;
      }
    }
    __syncthreads();
    #pragma unroll
    for (int cic = 0; cic < 8; ++cic) {
      const int s = p * 8 + cic;
      frag_u bu, au;
      bu.u = *(const uint4*)(wB + ((s * 32 + nt * 16 + (lane & 15)) * 32) + krow * 8);
      int lpx = mloc * 16 + (lane & 15);
      au.u = *(const uint4*)&sA[lpx * 256 + (((cic * 4 + krow) ^ (lpx & 7)) * 8)];
      acc = __builtin_amdgcn_mfma_f32_16x16x32_f16(au.v, bu.v, acc, 0, 0, 0);
    }
  }
  int co = nt * 16 + (lane & 15);
  #pragma unroll
  for (int r = 0; r < 4; ++r) {
    int px = ph + mloc * 16 + (lane >> 4) * 4 + r;
    int row = (b * 64 + h) * 64 + px;
    float v = acc[r];
    float o;
    if (co < 18) o = v + boff[co];
    else if (co < 27) { float mm = v + bmod[co - 18]; o = 2.f / (1.f + __expf(-mm)); }
    else o = 0.f;
    om[row * 32 + co] = o;
  }
}

// ---------------- deformable conv: 512 thr, 8 waves, pk_fma gather, global-B frags ----------------
// grid (8,64) = (b,h) -> XCD = b.
__global__ __launch_bounds__(512, 4) void k_deform(const ushort* __restrict__ an,
                                                   const float* __restrict__ om,
                                                   const ushort* __restrict__ wB,
                                                   ushort* __restrict__ ob,
                                                   float* __restrict__ part) {
  __shared__ __align__(16) ushort sA[64 * 256];
  const int b = blockIdx.x, h = blockIdx.y, t = threadIdx.x;
  const int lane = t & 63, wv = t >> 6;
  const int cow = wv * 32;
  const int krow = lane >> 4;
  const int spx = t & 63, seg = t >> 6;  // seg: 8 segments of 32 channels
  f32x4 acc[4][2];
  #pragma unroll
  for (int m = 0; m < 4; ++m)
    #pragma unroll
    for (int n = 0; n < 2; ++n) acc[m][n] = (f32x4){0.f, 0.f, 0.f, 0.f};

  const ushort* base = an + (size_t)b * PLANE * 256;
  const int row = (b * 64 + h) * 64 + spx;

  for (int p = 0; p < 9; ++p) {
    if (p) __syncthreads();
    {
      float dy = om[row * 32 + 2 * p];
      float dx = om[row * 32 + 2 * p + 1];
      float mk = om[row * 32 + 18 + p];
      float py = (float)(h + p / 3 - 1) + dy;
      float pxx = (float)(spx + p % 3 - 1) + dx;
      float fy = floorf(py), fx = floorf(pxx);
      float ly = py - fy, lx = pxx - fx;
      int y0 = (int)fy, x0 = (int)fx;
      bool vy0 = ((unsigned)y0 < 64u), vy1 = ((unsigned)(y0 + 1) < 64u);
      bool vx0 = ((unsigned)x0 < 64u), vx1 = ((unsigned)(x0 + 1) < 64u);
      float w00 = (1.f - ly) * (1.f - lx) * mk * ((vy0 && vx0) ? 1.f : 0.f);
      float w01 = (1.f - ly) * lx * mk * ((vy0 && vx1) ? 1.f : 0.f);
      float w10 = ly * (1.f - lx) * mk * ((vy1 && vx0) ? 1.f : 0.f);
      float w11 = ly * lx * mk * ((vy1 && vx1) ? 1.f : 0.f);
      __half2 w00h = __float2half2_rn(w00), w01h = __float2half2_rn(w01);
      __half2 w10h = __float2half2_rn(w10), w11h = __float2half2_rn(w11);
      int y0c = min(max(y0, 0), 63), y1c = min(max(y0 + 1, 0), 63);
      int x0c = min(max(x0, 0), 63), x1c = min(max(x0 + 1, 0), 63);
      const ushort* r00 = base + (y0c * 64 + x0c) * 256 + seg * 32;
      const ushort* r01 = base + (y0c * 64 + x1c) * 256 + seg * 32;
      const ushort* r10 = base + (y1c * 64 + x0c) * 256 + seg * 32;
      const ushort* r11 = base + (y1c * 64 + x1c) * 256 + seg * 32;
      #pragma unroll
      for (int j = 0; j < 4; ++j) {
        uint4 c00 = *(const uint4*)(r00 + j * 8);
        uint4 c01 = *(const uint4*)(r01 + j * 8);
        uint4 c10 = *(const uint4*)(r10 + j * 8);
        uint4 c11 = *(const uint4*)(r11 + j * 8);
        uint ou[4];
        #pragma unroll
        for (int q = 0; q < 4; ++q) {
          __half2 r2 = __hmul2(u2h2(((const uint*)&c00)[q]), w00h);
          r2 = __hfma2(u2h2(((const uint*)&c01)[q]), w01h, r2);
          r2 = __hfma2(u2h2(((const uint*)&c10)[q]), w10h, r2);
          r2 = __hfma2(u2h2(((const uint*)&c11)[q]), w11h, r2);
          ou[q] = h22u(r2);
        }
        *(uint4*)&sA[spx * 256 + (((seg * 4 + j) ^ (spx & 7)) * 8)] = *(uint4*)ou;
      }
    }
    __syncthreads();
    #pragma unroll
    for (int cic = 0; cic < 8; ++cic) {
      const int s = p * 8 + cic;
      frag_u bu[2], au[4];
      #pragma unroll
      for (int n = 0; n < 2; ++n)
        bu[n].u = *(const uint4*)(wB + ((s * 256 + cow + n * 16 + (lane & 15)) * 32) + krow * 8);
      #pragma unroll
      for (int m = 0; m < 4; ++m)
        au[m].u = *(const uint4*)&sA[(m * 16 + (lane & 15)) * 256 + (((cic * 4 + krow) ^ (lane & 7)) * 8)];
      #pragma unroll
      for (int m = 0; m < 4; ++m)
        #pragma unroll
        for (int n = 0; n < 2; ++n)
          acc[m][n] = __builtin_amdgcn_mfma_f32_16x16x32_f16(au[m].v, bu[n].v, acc[m][n], 0, 0, 0);
    }
  }
  const int blk = b * 64 + h;
  #pragma unroll
  for (int n = 0; n < 2; ++n) {
    float s1 = 0.f, s2 = 0.f;
    #pragma unroll
    for (int m = 0; m < 4; ++m)
      #pragma unroll
      for (int r = 0; r < 4; ++r) { float v = acc[m][n][r]; s1 += v; s2 += v * v; }
    s1 += __shfl_xor(s1, 16); s1 += __shfl_xor(s1, 32);
    s2 += __shfl_xor(s2, 16); s2 += __shfl_xor(s2, 32);
    if (lane < 16) {
      int co = cow + n * 16 + lane;
      part[co * 512 + blk] = s1;
      part[131072 + co * 512 + blk] = s2;
    }
  }
  __syncthreads();
  #pragma unroll
  for (int m = 0; m < 4; ++m) {
    int pxo = m * 16 + (lane >> 4) * 4;
    #pragma unroll
    for (int n = 0; n < 2; ++n) {
      int co = cow + n * 16 + (lane & 15);
      #pragma unroll
      for (int r = 0; r < 4; ++r)
        sA[(pxo + r) * 256 + co] = f2h(acc[m][n][r]);
    }
  }
  __syncthreads();
  const size_t row0 = (size_t)(b * 64 + h) * 64;
  const int chunk = t & 31, pr = t >> 5;
  #pragma unroll
  for (int j = 0; j < 4; ++j) {
    int px = j * 16 + pr;
    *(uint4*)&ob[(row0 + px) * 256 + chunk * 8] = *(const uint4*)&sA[px * 256 + chunk * 8];
  }
}

// ---------------- BN stats final reduce (part transposed: [2][256][512]) ----------------
__global__ void k_statB(const float* __restrict__ part, const float* __restrict__ g,
                        const float* __restrict__ bt, float* __restrict__ scale,
                        float* __restrict__ shift) {
  __shared__ float s2buf[256];
  const int tid = threadIdx.x;
  const int c = tid & 255, which = tid >> 8;
  const float4* p4 = (const float4*)(part + which * 131072 + c * 512);
  float s = 0.f;
  for (int r = 0; r < 128; ++r) { float4 v = p4[r]; s += v.x + v.y + v.z + v.w; }
  if (which) s2buf[c] = s;
  __syncthreads();
  if (!which) {
    const float inv = 1.f / 32768.f;
    float m = s * inv;
    float var = s2buf[c] * inv - m * m;
    float a = g[c] * rsqrtf(var + 1e-5f);
    scale[c] = a;
    shift[c] = bt[c] - m * a;
  }
}

// ---------------- BN+ReLU: t1 fp16 NHWC -> out1 fp16 NHWC ----------------
__global__ void k_bnrelu(const ushort* __restrict__ t, const float* __restrict__ scale,
                         const float* __restrict__ shift, ushort* __restrict__ o) {
  int stride = gridDim.x * blockDim.x;
  for (int i = blockIdx.x * blockDim.x + threadIdx.x; i < 8388608 / 8; i += stride) {
    uint4 v = ((const uint4*)t)[i];
    int c0 = (i & 31) * 8;
    uint ou[4];
    #pragma unroll
    for (int q = 0; q < 4; ++q) {
      float2 f = __half22float2(u2h2(((const uint*)&v)[q]));
      float sa = scale[c0 + 2 * q], sb = scale[c0 + 2 * q + 1];
      float ha = shift[c0 + 2 * q], hb = shift[c0 + 2 * q + 1];
      float qa = fmaxf(f.x * sa + ha, 0.f);
      float qb = fmaxf(f.y * sb + hb, 0.f);
      ou[q] = (uint)f2h(qa) | ((uint)f2h(qb) << 16);
    }
    ((uint4*)o)[i] = *(uint4*)ou;
  }
}

// ---------------- final: relu(bn2(t2)+bn3(res)), fp16 NHWC -> fp32 NCHW ----------------
__global__ __launch_bounds__(256) void k_final(const ushort* __restrict__ t2, const ushort* __restrict__ res,
                                               const float* __restrict__ s2p, const float* __restrict__ sh2p,
                                               const float* __restrict__ s3p, const float* __restrict__ sh3p,
                                               float* __restrict__ o) {
  __shared__ __align__(16) float sT[64 * 68];
  const int b = blockIdx.x, h = blockIdx.y, t = threadIdx.x;
  const int row0 = (b * 64 + h) * 64;
  for (int chunk = 0; chunk < 4; ++chunk) {
    const int c0 = chunk * 64;
    {
      int px = t >> 2, s4 = t & 3;
      int cl = s4 * 16;
      int rbase = (row0 + px) * 256 + c0 + cl;
      uint4 a0 = *(const uint4*)&t2[rbase];
      uint4 a1 = *(const uint4*)&t2[rbase + 8];
      uint4 r0 = *(const uint4*)&res[rbase];
      uint4 r1 = *(const uint4*)&res[rbase + 8];
      #pragma unroll
      for (int q = 0; q < 8; ++q) {
        uint ua = (q < 4) ? ((const uint*)&a0)[q] : ((const uint*)&a1)[q - 4];
        uint ur = (q < 4) ? ((const uint*)&r0)[q] : ((const uint*)&r1)[q - 4];
        float2 fa = __half22float2(u2h2(ua));
        float2 fr = __half22float2(u2h2(ur));
        int ce = cl + 2 * q, codd = ce + 1;
        sT[ce * 68 + px] = fmaxf(fa.x * s2p[c0 + ce] + sh2p[c0 + ce] + fr.x * s3p[c0 + ce] + sh3p[c0 + ce], 0.f);
        sT[codd * 68 + px] = fmaxf(fa.y * s2p[c0 + codd] + sh2p[c0 + codd] + fr.y * s3p[c0 + codd] + sh3p[c0 + codd], 0.f);
      }
    }
    __syncthreads();
    {
      int cl = t & 63, wseg = t >> 6;
      int obase = ((b * 256 + c0 + cl) * 64 + h) * 64 + wseg * 16;
      #pragma unroll
      for (int j = 0; j < 4; ++j) {
        float4 q;
        q.x = sT[cl * 68 + wseg * 16 + j * 4 + 0];
        q.y = sT[cl * 68 + wseg * 16 + j * 4 + 1];
        q.z = sT[cl * 68 + wseg * 16 + j * 4 + 2];
        q.w = sT[cl * 68 + wseg * 16 + j * 4 + 3];
        *(float4*)&o[obase + j * 4] = q;
      }
    }
    __syncthreads();
  }
}

extern "C" void kernel_launch(void* const* d_in, const int* in_sizes, int n_in,
                              void* d_out, int out_size, void* d_ws, size_t ws_size,
                              hipStream_t stream) {
  const float* x    = (const float*)d_in[0];
  const float* w1   = (const float*)d_in[2];
  const float* g1   = (const float*)d_in[4];
  const float* bt1  = (const float*)d_in[5];
  const float* woff = (const float*)d_in[6];
  const float* boff = (const float*)d_in[7];
  const float* wmod = (const float*)d_in[8];
  const float* bmod = (const float*)d_in[9];
  const float* wd   = (const float*)d_in[10];
  const float* g2   = (const float*)d_in[12];
  const float* bt2  = (const float*)d_in[13];
  const float* wds  = (const float*)d_in[14];
  const float* g3   = (const float*)d_in[16];
  const float* bt3  = (const float*)d_in[17];

  float* ws = (float*)d_ws;
  ushort* wb1   = (ushort*)ws;                   // 294912 f32
  ushort* wbd   = (ushort*)(ws + 294912);        // 294912
  ushort* wbom  = (ushort*)(ws + 589824);        // 36864
  ushort* wbds  = (ushort*)(ws + 626688);        // 32768
  float*  SC    = ws + 659456;                   // 2048
  float*  part1 = ws + 661504;                   // 262144
  float*  part2 = ws + 923648;                   // 262144
  float*  part3 = ws + 1185792;                  // 262144
  ushort* xn    = (ushort*)(ws + 1447936);       // 4194304
  ushort* out1  = (ushort*)(ws + 5642240);       // 4194304
  ushort* t1b   = (ushort*)(ws + 9836544);       // 4194304
  ushort* t2b   = (ushort*)(ws + 14030848);      // 4194304
  ushort* resb  = (ushort*)(ws + 18225152);      // 4194304
  float*  om    = ws + 22419456;                 // 1048576

  dim3 gbh(8, 64);
  k_prep<<<512, 256, 0, stream>>>(w1, wd, woff, wmod, wds, wb1, wbd, wbom, wbds);
  k_x2nhwc<<<gbh, 256, 0, stream>>>(x, xn);
  k_convbig<9><<<gbh, 512, 0, stream>>>(xn, wb1, t1b, part1);
  k_statB<<<1, 512, 0, stream>>>(part1, g1, bt1, SC, SC + 256);
  k_bnrelu<<<2048, 256, 0, stream>>>(t1b, SC, SC + 256, out1);
  k_convom<<<dim3(8, 128), 256, 0, stream>>>(out1, wbom, boff, bmod, om);
  k_deform<<<gbh, 512, 0, stream>>>(out1, om, wbd, t2b, part2);
  k_statB<<<1, 512, 0, stream>>>(part2, g2, bt2, SC + 512, SC + 768);
  k_convbig<1><<<gbh, 512, 0, stream>>>(xn, wbds, resb, part3);
  k_statB<<<1, 512, 0, stream>>>(part3, g3, bt3, SC + 1024, SC + 1280);
  k_final<<<gbh, 256, 0, stream>>>(t2b, resb, SC + 512, SC + 768, SC + 1024, SC + 1280, (float*)d_out);
}